// Round 12
// baseline (270.253 us; speedup 1.0000x reference)
//
#include <hip/hip_runtime.h>

#define C_DIM 128
#define HW_DIM 6144

typedef __attribute__((ext_vector_type(8))) short short8;
typedef __attribute__((ext_vector_type(4))) float f32x4;

static __device__ __forceinline__ unsigned short f2bf(float x) {
    unsigned int u = __builtin_bit_cast(unsigned int, x);
    u = (u + 0x7FFFu + ((u >> 16) & 1u)) >> 16;
    return (unsigned short)u;
}
static __device__ __forceinline__ float bf2f(unsigned short u) {
    unsigned int x = ((unsigned int)u) << 16;
    return __builtin_bit_cast(float, x);
}
static __device__ __forceinline__ f32x4 mfma_bf16(short8 a, short8 b, f32x4 c) {
    return __builtin_amdgcn_mfma_f32_16x16x32_bf16(a, b, c, 0, 0, 0);
}

// ---------------------------------------------------------------------------
// Fused 1x1-conv + BN + LeakyReLU GEMM (r11-proven v2 thread tiling).
// IN_MODE : 0 = X[b][c][hw] fp32, 1 = X[b][hw][c] fp32,
//           2 = COMBINE: x = (P0+P1+P2+P3)[pos][c] (bf16) * invL[pos]
// OUT_MODE: 0 fp32 [b][c][hw]; 1 bf16 [b][pos][c]*oscale; 2 bf16 [b][c][pos];
//           3 fp32 [b][c][hw] + residual
// ---------------------------------------------------------------------------
template<int IN_MODE, int OUT_MODE>
__global__ __launch_bounds__(256)
void conv_bn_lrelu(const void* __restrict__ Xv, const void* __restrict__ X2v,
                   const void* __restrict__ X3v, const void* __restrict__ X4v,
                   const float* __restrict__ Lp0, const float* __restrict__ Lp1,
                   const float* __restrict__ Lp2, const float* __restrict__ Lp3,
                   const float* __restrict__ W, const float* __restrict__ G,
                   const float* __restrict__ Bv, void* __restrict__ outp,
                   const float* __restrict__ resid, float oscale)
{
    __shared__ float Xs[32][36];
    __shared__ float Wt[32][132];
    __shared__ float invL[32];
    const int t  = threadIdx.x;
    const int b  = blockIdx.y;
    const int p0 = blockIdx.x * 32;
    const int pg = t & 7;
    const int og = t >> 3;
    const int pb = pg * 4;
    const int ob = og * 4;

    if (IN_MODE == 2) {
        if (t < 32) {
            size_t li = (size_t)b * HW_DIM + p0 + t;
            invL[t] = 1.0f / (Lp0[li] + Lp1[li] + Lp2[li] + Lp3[li]);
        }
        __syncthreads();
    }

    float acc[4][4];
#pragma unroll
    for (int i = 0; i < 4; ++i)
#pragma unroll
        for (int j = 0; j < 4; ++j) acc[i][j] = 0.f;

    for (int c0 = 0; c0 < C_DIM; c0 += 32) {
#pragma unroll
        for (int i = 0; i < 4; ++i) {
            int idx = t + 256 * i;
            if (IN_MODE == 0) {
                int cc = idx >> 5, pp = idx & 31;
                const float* Xb = (const float*)Xv + (size_t)b * C_DIM * HW_DIM;
                Xs[cc][pp] = Xb[(size_t)(c0 + cc) * HW_DIM + p0 + pp];
            } else if (IN_MODE == 1) {
                int pp = idx >> 5, cc = idx & 31;
                const float* Xb = (const float*)Xv + (size_t)b * C_DIM * HW_DIM;
                Xs[cc][pp] = Xb[(size_t)(p0 + pp) * C_DIM + c0 + cc];
            } else {
                int pp = idx >> 5, cc = idx & 31;
                size_t gi = ((size_t)b * HW_DIM + p0 + pp) * C_DIM + c0 + cc;
                float s = bf2f(((const unsigned short*)Xv)[gi])
                        + bf2f(((const unsigned short*)X2v)[gi])
                        + bf2f(((const unsigned short*)X3v)[gi])
                        + bf2f(((const unsigned short*)X4v)[gi]);
                Xs[cc][pp] = s * invL[pp];
            }
        }
#pragma unroll
        for (int i = 0; i < 16; ++i) {
            int idx = t + 256 * i;
            int o = idx >> 5, cc = idx & 31;
            Wt[cc][o] = W[o * C_DIM + c0 + cc];
        }
        __syncthreads();
#pragma unroll
        for (int cc = 0; cc < 32; ++cc) {
            float4 xv = *(const float4*)&Xs[cc][pb];
            float4 wv = *(const float4*)&Wt[cc][ob];
            acc[0][0] = fmaf(xv.x, wv.x, acc[0][0]);
            acc[0][1] = fmaf(xv.x, wv.y, acc[0][1]);
            acc[0][2] = fmaf(xv.x, wv.z, acc[0][2]);
            acc[0][3] = fmaf(xv.x, wv.w, acc[0][3]);
            acc[1][0] = fmaf(xv.y, wv.x, acc[1][0]);
            acc[1][1] = fmaf(xv.y, wv.y, acc[1][1]);
            acc[1][2] = fmaf(xv.y, wv.z, acc[1][2]);
            acc[1][3] = fmaf(xv.y, wv.w, acc[1][3]);
            acc[2][0] = fmaf(xv.z, wv.x, acc[2][0]);
            acc[2][1] = fmaf(xv.z, wv.y, acc[2][1]);
            acc[2][2] = fmaf(xv.z, wv.z, acc[2][2]);
            acc[2][3] = fmaf(xv.z, wv.w, acc[2][3]);
            acc[3][0] = fmaf(xv.w, wv.x, acc[3][0]);
            acc[3][1] = fmaf(xv.w, wv.y, acc[3][1]);
            acc[3][2] = fmaf(xv.w, wv.z, acc[3][2]);
            acc[3][3] = fmaf(xv.w, wv.w, acc[3][3]);
        }
        __syncthreads();
    }

    const float BNRS = 0.99999500003749972f;  // 1/sqrt(1 + 1e-5)
#pragma unroll
    for (int j = 0; j < 4; ++j) {
        int o = ob + j;
        float s = G[o] * BNRS, bb = Bv[o];
#pragma unroll
        for (int i = 0; i < 4; ++i) {
            float y = fmaf(acc[i][j], s, bb);
            acc[i][j] = y > 0.f ? y : 0.1f * y;
        }
    }

    if constexpr (OUT_MODE == 0) {
        float* O = (float*)outp;
#pragma unroll
        for (int j = 0; j < 4; ++j)
            *(float4*)&O[((size_t)b * C_DIM + ob + j) * HW_DIM + p0 + pb] =
                make_float4(acc[0][j], acc[1][j], acc[2][j], acc[3][j]);
    } else if constexpr (OUT_MODE == 1) {
        unsigned short* O = (unsigned short*)outp;
#pragma unroll
        for (int i = 0; i < 4; ++i) {
            ushort4 u = { f2bf(acc[i][0] * oscale), f2bf(acc[i][1] * oscale),
                          f2bf(acc[i][2] * oscale), f2bf(acc[i][3] * oscale) };
            *(ushort4*)&O[((size_t)b * HW_DIM + p0 + pb + i) * C_DIM + ob] = u;
        }
    } else if constexpr (OUT_MODE == 2) {
        unsigned short* O = (unsigned short*)outp;
#pragma unroll
        for (int j = 0; j < 4; ++j) {
            ushort4 u = { f2bf(acc[0][j]), f2bf(acc[1][j]),
                          f2bf(acc[2][j]), f2bf(acc[3][j]) };
            *(ushort4*)&O[((size_t)b * C_DIM + ob + j) * HW_DIM + p0 + pb] = u;
        }
    } else {
        float* O = (float*)outp;
#pragma unroll
        for (int j = 0; j < 4; ++j) {
            size_t i0 = ((size_t)b * C_DIM + ob + j) * HW_DIM + p0 + pb;
            float4 rv = *(const float4*)&resid[i0];
            *(float4*)&O[i0] = make_float4(acc[0][j] + rv.x, acc[1][j] + rv.y,
                                           acc[2][j] + rv.z, acc[3][j] + rv.w);
        }
    }
}

// ---------------------------------------------------------------------------
// Flash attention v4: XOR-swizzled LDS K/V tiles (conflict-free staging AND
// fragment reads), 192 q-rows/block (4 waves x 3 row-tiles), 4-way split-K,
// grid 256 = 2 batches x 32 q-blocks x 4 k-quarters -> exactly 1 block/CU
// (Plds over-sized so LDS 82 KB forbids 2-block packing). r11 accounting: DS
// pipe ~58 us + 8-way V-read conflicts was the binder; rt=3 cuts DS/row 1.5x,
// swizzle removes conflicts, split-K x4 cuts VMEM/CU to 0.75 MB (~23 us).
// Partials: UNNORMALIZED bf16 O-sums [b][pos][c] + fp32 row-sums; out-conv
// combines. Swizzle: 16B chunk c at row r stored at chunk c ^ (r & (NC-1));
// row stride == 0 mod 32 dwords makes bank = f(chunk') only -> even spread.
// ---------------------------------------------------------------------------
__global__ __launch_bounds__(256)
void flash_attn(const unsigned short* __restrict__ Q,
                const unsigned short* __restrict__ K,
                const unsigned short* __restrict__ V,
                unsigned short* __restrict__ P0, unsigned short* __restrict__ P1,
                unsigned short* __restrict__ P2, unsigned short* __restrict__ P3,
                float* __restrict__ L0, float* __restrict__ L1,
                float* __restrict__ L2, float* __restrict__ L3)
{
    __shared__ __align__(16) unsigned short Kt[2][64][128];   // 32 KB, swizzled
    __shared__ __align__(16) unsigned short Vt[2][128][64];   // 32 KB, swizzled
    __shared__ __align__(16) unsigned short Plds[8][16][72];  // 18 KB ([8] = occupancy clamp)
    const int tid  = threadIdx.x;
    const int wave = tid >> 6;
    const int lane = tid & 63;
    const int quad = lane >> 4;
    const int l16  = lane & 15;

    const int bid  = blockIdx.x;              // 0..255
    const int xcd  = bid & 7;
    const int b    = xcd >> 2;
    const int g    = xcd & 3;                 // XCD group within batch
    const int i    = bid >> 3;                // 0..31
    const int ks   = i >> 3;                  // k-quarter 0..3
    const int qblk = g * 8 + (i & 7);         // 0..31
    const int q0   = qblk * 192 + wave * 48;
    const int kbeg = ks * (HW_DIM / 4);

    unsigned short* __restrict__ Po = (ks == 0) ? P0 : (ks == 1) ? P1
                                    : (ks == 2) ? P2 : P3;
    float* __restrict__ Lo = (ks == 0) ? L0 : (ks == 1) ? L1
                           : (ks == 2) ? L2 : L3;

    const unsigned short* Qb = Q + (size_t)b * HW_DIM * C_DIM;
    const unsigned short* Kb = K + (size_t)b * HW_DIM * C_DIM;
    const unsigned short* Vb = V + (size_t)b * C_DIM * HW_DIM;

    // Q fragments for 3 row-tiles, register-resident
    short8 qf[3][4];
#pragma unroll
    for (int rt = 0; rt < 3; ++rt)
#pragma unroll
        for (int s = 0; s < 4; ++s)
            qf[rt][s] = *(const short8*)
                &Qb[(size_t)(q0 + rt * 16 + l16) * C_DIM + s * 32 + quad * 8];

    f32x4 O[3][8];
#pragma unroll
    for (int rt = 0; rt < 3; ++rt)
#pragma unroll
        for (int h = 0; h < 8; ++h) O[rt][h] = (f32x4){0.f, 0.f, 0.f, 0.f};
    float lsum[3][4] = {{0,0,0,0},{0,0,0,0},{0,0,0,0}};

    // initial tile staging. K chunk ck: pos=ck>>4, c16=ck&15 (16 chunks/row).
    // V chunk cv: ch=cv>>3, p8=cv&7 (8 chunks/row). Swizzled LDS placement.
    uint4 kst[4], vst[4];
#pragma unroll
    for (int j = 0; j < 4; ++j) {
        int ck = tid + 256 * j;
        kst[j] = *(const uint4*)&Kb[(size_t)(kbeg + (ck >> 4)) * C_DIM + (ck & 15) * 8];
        vst[j] = *(const uint4*)&Vb[(size_t)(ck >> 3) * HW_DIM + kbeg + (ck & 7) * 8];
    }
#pragma unroll
    for (int j = 0; j < 4; ++j) {
        int ck = tid + 256 * j;
        *(uint4*)&Kt[0][ck >> 4][(((ck & 15) ^ ((ck >> 4) & 15))) * 8] = kst[j];
        *(uint4*)&Vt[0][ck >> 3][(((ck & 7) ^ ((ck >> 3) & 7))) * 8]   = vst[j];
    }

    const int NIT = (HW_DIM / 4) / 64;   // 24
    for (int it = 0; it < NIT; ++it) {
        const int cur = it & 1;
        __syncthreads();

        const int kb2 = kbeg + (it + 1) * 64;
        if (it + 1 < NIT) {
#pragma unroll
            for (int j = 0; j < 4; ++j) {
                int ck = tid + 256 * j;
                kst[j] = *(const uint4*)
                    &Kb[(size_t)(kb2 + (ck >> 4)) * C_DIM + (ck & 15) * 8];
                vst[j] = *(const uint4*)
                    &Vb[(size_t)(ck >> 3) * HW_DIM + kb2 + (ck & 7) * 8];
            }
        }

        // ---- S = Q*K^T; 3 row-tiles share each K-fragment read ----
        f32x4 S[3][4];
#pragma unroll
        for (int rt = 0; rt < 3; ++rt)
#pragma unroll
            for (int n = 0; n < 4; ++n) S[rt][n] = (f32x4){0.f, 0.f, 0.f, 0.f};
#pragma unroll
        for (int n = 0; n < 4; ++n)
#pragma unroll
            for (int s = 0; s < 4; ++s) {
                short8 kf = *(const short8*)
                    &Kt[cur][n * 16 + l16][((4 * s + quad) ^ l16) * 8];
                S[0][n] = mfma_bf16(qf[0][s], kf, S[0][n]);
                S[1][n] = mfma_bf16(qf[1][s], kf, S[1][n]);
                S[2][n] = mfma_bf16(qf[2][s], kf, S[2][n]);
            }

        // ---- fixed-shift softmax; P via per-wave LDS region (sequential
        //      rt reuse is safe: DS ops are wave-ordered) ----
        short8 pa[3][2];
#pragma unroll
        for (int rt = 0; rt < 3; ++rt) {
#pragma unroll
            for (int n = 0; n < 4; ++n)
#pragma unroll
                for (int r = 0; r < 4; ++r) {
                    float e = __builtin_amdgcn_exp2f(S[rt][n][r]);
                    lsum[rt][r] += e;
                    Plds[wave][quad * 4 + r][n * 16 + l16] = f2bf(e);
                }
            pa[rt][0] = *(const short8*)&Plds[wave][l16][quad * 8];
            pa[rt][1] = *(const short8*)&Plds[wave][l16][32 + quad * 8];
        }

        // ---- O += P*V^T; 3 row-tiles share each V-fragment read ----
#pragma unroll
        for (int h = 0; h < 8; ++h) {
            const int m = l16 & 7;
            short8 v0 = *(const short8*)&Vt[cur][h * 16 + l16][(quad ^ m) * 8];
            short8 v1 = *(const short8*)&Vt[cur][h * 16 + l16][((quad + 4) ^ m) * 8];
            O[0][h] = mfma_bf16(pa[0][0], v0, O[0][h]);
            O[0][h] = mfma_bf16(pa[0][1], v1, O[0][h]);
            O[1][h] = mfma_bf16(pa[1][0], v0, O[1][h]);
            O[1][h] = mfma_bf16(pa[1][1], v1, O[1][h]);
            O[2][h] = mfma_bf16(pa[2][0], v0, O[2][h]);
            O[2][h] = mfma_bf16(pa[2][1], v1, O[2][h]);
        }

        if (it + 1 < NIT) {
            const int nxt = cur ^ 1;
#pragma unroll
            for (int j = 0; j < 4; ++j) {
                int ck = tid + 256 * j;
                *(uint4*)&Kt[nxt][ck >> 4][(((ck & 15) ^ ((ck >> 4) & 15))) * 8] = kst[j];
                *(uint4*)&Vt[nxt][ck >> 3][(((ck & 7) ^ ((ck >> 3) & 7))) * 8]   = vst[j];
            }
        }
    }

    // ---- row-sum reduction over 16 lanes; emit UNNORMALIZED partials ----
#pragma unroll
    for (int off = 1; off < 16; off <<= 1)
#pragma unroll
        for (int rt = 0; rt < 3; ++rt)
#pragma unroll
            for (int r = 0; r < 4; ++r)
                lsum[rt][r] += __shfl_xor(lsum[rt][r], off, 64);

#pragma unroll
    for (int rt = 0; rt < 3; ++rt)
#pragma unroll
        for (int r = 0; r < 4; ++r) {
            size_t row = (size_t)b * HW_DIM + q0 + rt * 16 + quad * 4 + r;
            if (l16 == 0) Lo[row] = lsum[rt][r];
#pragma unroll
            for (int h = 0; h < 8; ++h)
                Po[row * C_DIM + h * 16 + l16] = f2bf(O[rt][h][r]);
        }
}

// ---------------------------------------------------------------------------
extern "C" void kernel_launch(void* const* d_in, const int* in_sizes, int n_in,
                              void* d_out, int out_size, void* d_ws, size_t ws_size,
                              hipStream_t stream)
{
    const float* query = (const float*)d_in[0];
    const float* key   = (const float*)d_in[1];
    const float* q_w1 = (const float*)d_in[2];
    const float* q_g1 = (const float*)d_in[3];
    const float* q_b1 = (const float*)d_in[4];
    const float* q_w2 = (const float*)d_in[5];
    const float* q_g2 = (const float*)d_in[6];
    const float* q_b2 = (const float*)d_in[7];
    const float* k_w1 = (const float*)d_in[8];
    const float* k_g1 = (const float*)d_in[9];
    const float* k_b1 = (const float*)d_in[10];
    const float* k_w2 = (const float*)d_in[11];
    const float* k_g2 = (const float*)d_in[12];
    const float* k_b2 = (const float*)d_in[13];
    const float* v_w  = (const float*)d_in[14];
    const float* v_g  = (const float*)d_in[15];
    const float* v_b  = (const float*)d_in[16];
    const float* o_w  = (const float*)d_in[17];
    const float* o_g  = (const float*)d_in[18];
    const float* o_b  = (const float*)d_in[19];

    // workspace: y1 (6 MB fp32, dead after convs) is reused for P0+P1 (bf16).
    char* ws = (char*)d_ws;
    float*          y1  = (float*)ws;                                   // [0, 6 MB)
    unsigned short* P0  = (unsigned short*)ws;                          // 3 MB
    unsigned short* P1  = (unsigned short*)(ws + 3145728);              // 3 MB
    unsigned short* Qbf = (unsigned short*)(ws + 6291456);              // 3 MB
    unsigned short* Kbf = (unsigned short*)(ws + 6291456 + 3145728);    // 3 MB
    unsigned short* Vbf = (unsigned short*)(ws + 6291456 + 2 * 3145728);// 3 MB
    unsigned short* P2  = (unsigned short*)(ws + 6291456 + 3 * 3145728);// 3 MB
    unsigned short* P3  = (unsigned short*)(ws + 6291456 + 4 * 3145728);// 3 MB
    float*          L0  = (float*)(ws + 6291456 + 5 * 3145728);         // 48 KB x4
    float*          L1  = L0 + HW_DIM * 2;
    float*          L2  = L1 + HW_DIM * 2;
    float*          L3  = L2 + HW_DIM * 2;
    float* outp = (float*)d_out;

    const float qscale = 0.08838834764831845f * 1.44269504088896340f;

    dim3 cgrid(HW_DIM / 32, 2), cblk(256);
    hipLaunchKernelGGL((conv_bn_lrelu<0, 0>), cgrid, cblk, 0, stream,
                       query, nullptr, nullptr, nullptr,
                       nullptr, nullptr, nullptr, nullptr,
                       q_w1, q_g1, q_b1, (void*)y1, nullptr, 1.0f);
    hipLaunchKernelGGL((conv_bn_lrelu<0, 1>), cgrid, cblk, 0, stream,
                       y1, nullptr, nullptr, nullptr,
                       nullptr, nullptr, nullptr, nullptr,
                       q_w2, q_g2, q_b2, (void*)Qbf, nullptr, qscale);
    hipLaunchKernelGGL((conv_bn_lrelu<0, 0>), cgrid, cblk, 0, stream,
                       key, nullptr, nullptr, nullptr,
                       nullptr, nullptr, nullptr, nullptr,
                       k_w1, k_g1, k_b1, (void*)y1, nullptr, 1.0f);
    hipLaunchKernelGGL((conv_bn_lrelu<0, 1>), cgrid, cblk, 0, stream,
                       y1, nullptr, nullptr, nullptr,
                       nullptr, nullptr, nullptr, nullptr,
                       k_w2, k_g2, k_b2, (void*)Kbf, nullptr, 1.0f);
    hipLaunchKernelGGL((conv_bn_lrelu<0, 2>), cgrid, cblk, 0, stream,
                       key, nullptr, nullptr, nullptr,
                       nullptr, nullptr, nullptr, nullptr,
                       v_w, v_g, v_b, (void*)Vbf, nullptr, 1.0f);

    // Flash: 192 q-rows/block x 4 k-quarters, grid 256 (XCD-affine, balanced).
    hipLaunchKernelGGL(flash_attn, dim3(256), dim3(256), 0, stream,
                       Qbf, Kbf, Vbf, P0, P1, P2, P3, L0, L1, L2, L3);

    // Out-projection: combines the 4 bf16 split-K partials + residual.
    hipLaunchKernelGGL((conv_bn_lrelu<2, 3>), cgrid, cblk, 0, stream,
                       P0, P1, P2, P3, L0, L1, L2, L3,
                       o_w, o_g, o_b, (void*)outp, query, 1.0f);
}

// Round 13
// 247.459 us; speedup vs baseline: 1.0921x; 1.0921x over previous
//
#include <hip/hip_runtime.h>

#define C_DIM 128
#define HW_DIM 6144

typedef __attribute__((ext_vector_type(8))) short short8;
typedef __attribute__((ext_vector_type(4))) float f32x4;

static __device__ __forceinline__ unsigned short f2bf(float x) {
    unsigned int u = __builtin_bit_cast(unsigned int, x);
    u = (u + 0x7FFFu + ((u >> 16) & 1u)) >> 16;
    return (unsigned short)u;
}
static __device__ __forceinline__ float bf2f(unsigned short u) {
    unsigned int x = ((unsigned int)u) << 16;
    return __builtin_bit_cast(float, x);
}
static __device__ __forceinline__ f32x4 mfma_bf16(short8 a, short8 b, f32x4 c) {
    return __builtin_amdgcn_mfma_f32_16x16x32_bf16(a, b, c, 0, 0, 0);
}

// ---------------------------------------------------------------------------
// Batched 1x1-conv + BN + LeakyReLU: blockIdx.z selects one of <=3 jobs.
// All jobs read X[b][c][hw] fp32 (IN_MODE 0). out_mode per job:
//   0 fp32 [b][c][hw]; 1 bf16 [b][pos][c]*oscale; 2 bf16 [b][c][pos].
// v2 thread tiling (r11/r12-proven): 4 pos x 4 out per thread, float4 LDS.
// ---------------------------------------------------------------------------
struct ConvJobs {
    const float* X[3]; const float* W[3];
    const float* G[3]; const float* B[3];
    void* out[3]; float oscale[3]; int out_mode[3];
};

__global__ __launch_bounds__(256)
void conv_jobs(ConvJobs jb)
{
    const int z = blockIdx.z;
    const float* X = jb.X[z]; const float* W = jb.W[z];
    const float* G = jb.G[z]; const float* Bv = jb.B[z];
    void* outp = jb.out[z];
    const float oscale = jb.oscale[z];
    const int out_mode = jb.out_mode[z];

    __shared__ float Xs[32][36];
    __shared__ float Wt[32][132];
    const int t  = threadIdx.x;
    const int b  = blockIdx.y;
    const int p0 = blockIdx.x * 32;
    const int pg = t & 7;
    const int og = t >> 3;
    const int pb = pg * 4;
    const int ob = og * 4;

    float acc[4][4];
#pragma unroll
    for (int i = 0; i < 4; ++i)
#pragma unroll
        for (int j = 0; j < 4; ++j) acc[i][j] = 0.f;

    const float* Xb = X + (size_t)b * C_DIM * HW_DIM;

    for (int c0 = 0; c0 < C_DIM; c0 += 32) {
#pragma unroll
        for (int i = 0; i < 4; ++i) {
            int idx = t + 256 * i;
            int cc = idx >> 5, pp = idx & 31;
            Xs[cc][pp] = Xb[(size_t)(c0 + cc) * HW_DIM + p0 + pp];
        }
#pragma unroll
        for (int i = 0; i < 16; ++i) {
            int idx = t + 256 * i;
            int o = idx >> 5, cc = idx & 31;
            Wt[cc][o] = W[o * C_DIM + c0 + cc];
        }
        __syncthreads();
#pragma unroll
        for (int cc = 0; cc < 32; ++cc) {
            float4 xv = *(const float4*)&Xs[cc][pb];
            float4 wv = *(const float4*)&Wt[cc][ob];
            acc[0][0] = fmaf(xv.x, wv.x, acc[0][0]);
            acc[0][1] = fmaf(xv.x, wv.y, acc[0][1]);
            acc[0][2] = fmaf(xv.x, wv.z, acc[0][2]);
            acc[0][3] = fmaf(xv.x, wv.w, acc[0][3]);
            acc[1][0] = fmaf(xv.y, wv.x, acc[1][0]);
            acc[1][1] = fmaf(xv.y, wv.y, acc[1][1]);
            acc[1][2] = fmaf(xv.y, wv.z, acc[1][2]);
            acc[1][3] = fmaf(xv.y, wv.w, acc[1][3]);
            acc[2][0] = fmaf(xv.z, wv.x, acc[2][0]);
            acc[2][1] = fmaf(xv.z, wv.y, acc[2][1]);
            acc[2][2] = fmaf(xv.z, wv.z, acc[2][2]);
            acc[2][3] = fmaf(xv.z, wv.w, acc[2][3]);
            acc[3][0] = fmaf(xv.w, wv.x, acc[3][0]);
            acc[3][1] = fmaf(xv.w, wv.y, acc[3][1]);
            acc[3][2] = fmaf(xv.w, wv.z, acc[3][2]);
            acc[3][3] = fmaf(xv.w, wv.w, acc[3][3]);
        }
        __syncthreads();
    }

    const float BNRS = 0.99999500003749972f;  // 1/sqrt(1 + 1e-5)
#pragma unroll
    for (int j = 0; j < 4; ++j) {
        int o = ob + j;
        float s = G[o] * BNRS, bb = Bv[o];
#pragma unroll
        for (int i = 0; i < 4; ++i) {
            float y = fmaf(acc[i][j], s, bb);
            acc[i][j] = y > 0.f ? y : 0.1f * y;
        }
    }

    if (out_mode == 0) {
        float* O = (float*)outp;
#pragma unroll
        for (int j = 0; j < 4; ++j)
            *(float4*)&O[((size_t)b * C_DIM + ob + j) * HW_DIM + p0 + pb] =
                make_float4(acc[0][j], acc[1][j], acc[2][j], acc[3][j]);
    } else if (out_mode == 1) {
        unsigned short* O = (unsigned short*)outp;
#pragma unroll
        for (int i = 0; i < 4; ++i) {
            ushort4 u = { f2bf(acc[i][0] * oscale), f2bf(acc[i][1] * oscale),
                          f2bf(acc[i][2] * oscale), f2bf(acc[i][3] * oscale) };
            *(ushort4*)&O[((size_t)b * HW_DIM + p0 + pb + i) * C_DIM + ob] = u;
        }
    } else {
        unsigned short* O = (unsigned short*)outp;
#pragma unroll
        for (int j = 0; j < 4; ++j) {
            ushort4 u = { f2bf(acc[0][j]), f2bf(acc[1][j]),
                          f2bf(acc[2][j]), f2bf(acc[3][j]) };
            *(ushort4*)&O[((size_t)b * C_DIM + ob + j) * HW_DIM + p0 + pb] = u;
        }
    }
}

// ---------------------------------------------------------------------------
// Combine conv: x = (P0+P1+P2+P3)[pos][c] (bf16, uint2-vectorized) * invL,
// then 1x1-conv + BN + LReLU + residual -> fp32 [b][c][hw].
// ---------------------------------------------------------------------------
__global__ __launch_bounds__(256)
void conv_combine(const unsigned short* __restrict__ P0,
                  const unsigned short* __restrict__ P1,
                  const unsigned short* __restrict__ P2,
                  const unsigned short* __restrict__ P3,
                  const float* __restrict__ L0, const float* __restrict__ L1,
                  const float* __restrict__ L2, const float* __restrict__ L3,
                  const float* __restrict__ W, const float* __restrict__ G,
                  const float* __restrict__ Bv, float* __restrict__ outp,
                  const float* __restrict__ resid)
{
    __shared__ float Xs[32][36];
    __shared__ float Wt[32][132];
    __shared__ float invL[32];
    const int t  = threadIdx.x;
    const int b  = blockIdx.y;
    const int p0 = blockIdx.x * 32;
    const int pg = t & 7;
    const int og = t >> 3;
    const int pb = pg * 4;
    const int ob = og * 4;

    if (t < 32) {
        size_t li = (size_t)b * HW_DIM + p0 + t;
        invL[t] = 1.0f / (L0[li] + L1[li] + L2[li] + L3[li]);
    }
    __syncthreads();

    float acc[4][4];
#pragma unroll
    for (int i = 0; i < 4; ++i)
#pragma unroll
        for (int j = 0; j < 4; ++j) acc[i][j] = 0.f;

    const int pp = t & 31;       // position slot for staging
    const int cq = t >> 5;       // channel quad 0..7

    for (int c0 = 0; c0 < C_DIM; c0 += 32) {
        {
            size_t gi = ((size_t)b * HW_DIM + p0 + pp) * C_DIM + c0 + cq * 4;
            uint2 a0 = *(const uint2*)&P0[gi];
            uint2 a1 = *(const uint2*)&P1[gi];
            uint2 a2 = *(const uint2*)&P2[gi];
            uint2 a3 = *(const uint2*)&P3[gi];
            float s = invL[pp];
#pragma unroll
            for (int j = 0; j < 4; ++j) {
                unsigned int w0 = (j < 2) ? a0.x : a0.y;
                unsigned int w1 = (j < 2) ? a1.x : a1.y;
                unsigned int w2 = (j < 2) ? a2.x : a2.y;
                unsigned int w3 = (j < 2) ? a3.x : a3.y;
                int sh = (j & 1) * 16;
                float v = bf2f((unsigned short)(w0 >> sh))
                        + bf2f((unsigned short)(w1 >> sh))
                        + bf2f((unsigned short)(w2 >> sh))
                        + bf2f((unsigned short)(w3 >> sh));
                Xs[cq * 4 + j][pp] = v * s;
            }
        }
#pragma unroll
        for (int i = 0; i < 16; ++i) {
            int idx = t + 256 * i;
            int o = idx >> 5, cc = idx & 31;
            Wt[cc][o] = W[o * C_DIM + c0 + cc];
        }
        __syncthreads();
#pragma unroll
        for (int cc = 0; cc < 32; ++cc) {
            float4 xv = *(const float4*)&Xs[cc][pb];
            float4 wv = *(const float4*)&Wt[cc][ob];
            acc[0][0] = fmaf(xv.x, wv.x, acc[0][0]);
            acc[0][1] = fmaf(xv.x, wv.y, acc[0][1]);
            acc[0][2] = fmaf(xv.x, wv.z, acc[0][2]);
            acc[0][3] = fmaf(xv.x, wv.w, acc[0][3]);
            acc[1][0] = fmaf(xv.y, wv.x, acc[1][0]);
            acc[1][1] = fmaf(xv.y, wv.y, acc[1][1]);
            acc[1][2] = fmaf(xv.y, wv.z, acc[1][2]);
            acc[1][3] = fmaf(xv.y, wv.w, acc[1][3]);
            acc[2][0] = fmaf(xv.z, wv.x, acc[2][0]);
            acc[2][1] = fmaf(xv.z, wv.y, acc[2][1]);
            acc[2][2] = fmaf(xv.z, wv.z, acc[2][2]);
            acc[2][3] = fmaf(xv.z, wv.w, acc[2][3]);
            acc[3][0] = fmaf(xv.w, wv.x, acc[3][0]);
            acc[3][1] = fmaf(xv.w, wv.y, acc[3][1]);
            acc[3][2] = fmaf(xv.w, wv.z, acc[3][2]);
            acc[3][3] = fmaf(xv.w, wv.w, acc[3][3]);
        }
        __syncthreads();
    }

    const float BNRS = 0.99999500003749972f;
#pragma unroll
    for (int j = 0; j < 4; ++j) {
        int o = ob + j;
        float s = G[o] * BNRS, bb = Bv[o];
#pragma unroll
        for (int i = 0; i < 4; ++i) {
            float y = fmaf(acc[i][j], s, bb);
            acc[i][j] = y > 0.f ? y : 0.1f * y;
        }
    }
#pragma unroll
    for (int j = 0; j < 4; ++j) {
        size_t i0 = ((size_t)b * C_DIM + ob + j) * HW_DIM + p0 + pb;
        float4 rv = *(const float4*)&resid[i0];
        *(float4*)&outp[i0] = make_float4(acc[0][j] + rv.x, acc[1][j] + rv.y,
                                          acc[2][j] + rv.z, acc[3][j] + rv.w);
    }
}

// ---------------------------------------------------------------------------
// Flash attention v5: 512 threads = 2 wave-GROUPS of 4 waves. Groups split
// the block's k-quarter into two eighths, each with its own single-buffered
// XOR-swizzled K/V tile (cross-group TLP = 2 waves/SIMD replaces r12's
// double buffer; r12 showed 1 wave/SIMD serializes all pipes: 110 us vs
// DS-floor 34 us). rt=3 row-tiles/wave (r12-proven frag-read amortization),
// 4-way split-K, grid 256 = 1 block/CU (LDS 82 KB). Group B's partial is
// combined into group A's through the dead tile-LDS at the end; blocks emit
// the same 4 global bf16 partial buffers + fp32 row-sums as r12.
// ---------------------------------------------------------------------------
__global__ __launch_bounds__(512, 2)
void flash_attn(const unsigned short* __restrict__ Q,
                const unsigned short* __restrict__ K,
                const unsigned short* __restrict__ V,
                unsigned short* __restrict__ P0, unsigned short* __restrict__ P1,
                unsigned short* __restrict__ P2, unsigned short* __restrict__ P3,
                float* __restrict__ L0, float* __restrict__ L1,
                float* __restrict__ L2, float* __restrict__ L3)
{
    // per group: K tile [64 pos][128 ch] + V tile [128 ch][64 pos], swizzled
    __shared__ __align__(16) unsigned short TM[2][16384];     // 64 KB
    __shared__ __align__(16) unsigned short Plds[8][16][72];  // 18 KB
    const int tid  = threadIdx.x;
    const int wave = tid >> 6;          // 0..7
    const int gid  = wave >> 2;         // k-eighth group
    const int wl   = wave & 3;          // wave within group
    const int gtid = tid & 255;
    const int lane = tid & 63;
    const int quad = lane >> 4;
    const int l16  = lane & 15;

    const int bid  = blockIdx.x;              // 0..255
    const int xcd  = bid & 7;
    const int b    = xcd >> 2;
    const int g3   = xcd & 3;
    const int i    = bid >> 3;                // 0..31
    const int ks   = i >> 3;                  // k-quarter 0..3
    const int qblk = g3 * 8 + (i & 7);        // 0..31
    const int q0   = qblk * 192 + wl * 48;
    const int kbeg = ks * (HW_DIM / 4) + gid * (HW_DIM / 8);

    unsigned short* __restrict__ Po = (ks == 0) ? P0 : (ks == 1) ? P1
                                    : (ks == 2) ? P2 : P3;
    float* __restrict__ Lo = (ks == 0) ? L0 : (ks == 1) ? L1
                           : (ks == 2) ? L2 : L3;

    const unsigned short* Qb = Q + (size_t)b * HW_DIM * C_DIM;
    const unsigned short* Kb = K + (size_t)b * HW_DIM * C_DIM;
    const unsigned short* Vb = V + (size_t)b * C_DIM * HW_DIM;

    unsigned short* Kt = TM[gid];             // [pos*128 + chunk*8]
    unsigned short* Vt = TM[gid] + 8192;      // [ch*64 + chunk*8]

    short8 qf[3][4];
#pragma unroll
    for (int rt = 0; rt < 3; ++rt)
#pragma unroll
        for (int s = 0; s < 4; ++s)
            qf[rt][s] = *(const short8*)
                &Qb[(size_t)(q0 + rt * 16 + l16) * C_DIM + s * 32 + quad * 8];

    f32x4 O[3][8];
#pragma unroll
    for (int rt = 0; rt < 3; ++rt)
#pragma unroll
        for (int h = 0; h < 8; ++h) O[rt][h] = (f32x4){0.f, 0.f, 0.f, 0.f};
    float lsum[3][4] = {{0,0,0,0},{0,0,0,0},{0,0,0,0}};

    // prologue: load tile 0 into regs
    uint4 kst[4], vst[4];
#pragma unroll
    for (int j = 0; j < 4; ++j) {
        int ck = gtid + 256 * j;
        kst[j] = *(const uint4*)&Kb[(size_t)(kbeg + (ck >> 4)) * C_DIM + (ck & 15) * 8];
        vst[j] = *(const uint4*)&Vb[(size_t)(ck >> 3) * HW_DIM + kbeg + (ck & 7) * 8];
    }

    const int NIT = (HW_DIM / 8) / 64;   // 12
    for (int it = 0; it < NIT; ++it) {
        // write staged regs -> LDS (swizzled), then barrier
#pragma unroll
        for (int j = 0; j < 4; ++j) {
            int ck = gtid + 256 * j;
            *(uint4*)&Kt[(size_t)(ck >> 4) * 128 + (((ck & 15) ^ ((ck >> 4) & 15)) * 8)] = kst[j];
            *(uint4*)&Vt[(size_t)(ck >> 3) * 64 + (((ck & 7) ^ ((ck >> 3) & 7)) * 8)]   = vst[j];
        }
        __syncthreads();

        // issue next tile's global loads (in flight during compute)
        if (it + 1 < NIT) {
            const int kb2 = kbeg + (it + 1) * 64;
#pragma unroll
            for (int j = 0; j < 4; ++j) {
                int ck = gtid + 256 * j;
                kst[j] = *(const uint4*)
                    &Kb[(size_t)(kb2 + (ck >> 4)) * C_DIM + (ck & 15) * 8];
                vst[j] = *(const uint4*)
                    &Vb[(size_t)(ck >> 3) * HW_DIM + kb2 + (ck & 7) * 8];
            }
        }

        // S = Q*K^T; 3 row-tiles share each K-fragment read
        f32x4 S[3][4];
#pragma unroll
        for (int rt = 0; rt < 3; ++rt)
#pragma unroll
            for (int n = 0; n < 4; ++n) S[rt][n] = (f32x4){0.f, 0.f, 0.f, 0.f};
#pragma unroll
        for (int n = 0; n < 4; ++n)
#pragma unroll
            for (int s = 0; s < 4; ++s) {
                short8 kf = *(const short8*)
                    &Kt[(size_t)(n * 16 + l16) * 128 + (((4 * s + quad) ^ l16) * 8)];
                S[0][n] = mfma_bf16(qf[0][s], kf, S[0][n]);
                S[1][n] = mfma_bf16(qf[1][s], kf, S[1][n]);
                S[2][n] = mfma_bf16(qf[2][s], kf, S[2][n]);
            }

        // fixed-shift softmax; P via per-wave LDS region
        short8 pa[3][2];
#pragma unroll
        for (int rt = 0; rt < 3; ++rt) {
#pragma unroll
            for (int n = 0; n < 4; ++n)
#pragma unroll
                for (int r = 0; r < 4; ++r) {
                    float e = __builtin_amdgcn_exp2f(S[rt][n][r]);
                    lsum[rt][r] += e;
                    Plds[wave][quad * 4 + r][n * 16 + l16] = f2bf(e);
                }
            pa[rt][0] = *(const short8*)&Plds[wave][l16][quad * 8];
            pa[rt][1] = *(const short8*)&Plds[wave][l16][32 + quad * 8];
        }

        // O += P*V^T; 3 row-tiles share each V-fragment read
        const int m = l16 & 7;
#pragma unroll
        for (int h = 0; h < 8; ++h) {
            short8 v0 = *(const short8*)&Vt[(size_t)(h * 16 + l16) * 64 + ((quad ^ m) * 8)];
            short8 v1 = *(const short8*)&Vt[(size_t)(h * 16 + l16) * 64 + (((quad + 4) ^ m) * 8)];
            O[0][h] = mfma_bf16(pa[0][0], v0, O[0][h]);
            O[0][h] = mfma_bf16(pa[0][1], v1, O[0][h]);
            O[1][h] = mfma_bf16(pa[1][0], v0, O[1][h]);
            O[1][h] = mfma_bf16(pa[1][1], v1, O[1][h]);
            O[2][h] = mfma_bf16(pa[2][0], v0, O[2][h]);
            O[2][h] = mfma_bf16(pa[2][1], v1, O[2][h]);
        }
        __syncthreads();   // tile consumed; next iter may overwrite
    }

    // row-sum reduction over 16 lanes
#pragma unroll
    for (int off = 1; off < 16; off <<= 1)
#pragma unroll
        for (int rt = 0; rt < 3; ++rt)
#pragma unroll
            for (int r = 0; r < 4; ++r)
                lsum[rt][r] += __shfl_xor(lsum[rt][r], off, 64);

    // ---- block-internal combine: group B -> LDS, group A sums + writes ----
    unsigned short* CB = &TM[0][0];        // [192][132] bf16 (50.7 KB)
    float* Lsh = (float*)&Plds[0][0][0];   // [192] fp32
    __syncthreads();                       // tiles dead, Plds dead
    if (gid == 1) {
#pragma unroll
        for (int rt = 0; rt < 3; ++rt)
#pragma unroll
            for (int r = 0; r < 4; ++r) {
                int lrow = wl * 48 + rt * 16 + quad * 4 + r;
                if (l16 == 0) Lsh[lrow] = lsum[rt][r];
#pragma unroll
                for (int h = 0; h < 8; ++h)
                    CB[lrow * 132 + h * 16 + l16] = f2bf(O[rt][h][r]);
            }
    }
    __syncthreads();
    if (gid == 0) {
#pragma unroll
        for (int rt = 0; rt < 3; ++rt)
#pragma unroll
            for (int r = 0; r < 4; ++r) {
                int lrow = wl * 48 + rt * 16 + quad * 4 + r;
                size_t row = (size_t)b * HW_DIM + qblk * 192 + lrow;
                if (l16 == 0) Lo[row] = lsum[rt][r] + Lsh[lrow];
#pragma unroll
                for (int h = 0; h < 8; ++h) {
                    float s = O[rt][h][r] + bf2f(CB[lrow * 132 + h * 16 + l16]);
                    Po[row * C_DIM + h * 16 + l16] = f2bf(s);
                }
            }
    }
}

// ---------------------------------------------------------------------------
extern "C" void kernel_launch(void* const* d_in, const int* in_sizes, int n_in,
                              void* d_out, int out_size, void* d_ws, size_t ws_size,
                              hipStream_t stream)
{
    const float* query = (const float*)d_in[0];
    const float* key   = (const float*)d_in[1];
    const float* q_w1 = (const float*)d_in[2];
    const float* q_g1 = (const float*)d_in[3];
    const float* q_b1 = (const float*)d_in[4];
    const float* q_w2 = (const float*)d_in[5];
    const float* q_g2 = (const float*)d_in[6];
    const float* q_b2 = (const float*)d_in[7];
    const float* k_w1 = (const float*)d_in[8];
    const float* k_g1 = (const float*)d_in[9];
    const float* k_b1 = (const float*)d_in[10];
    const float* k_w2 = (const float*)d_in[11];
    const float* k_g2 = (const float*)d_in[12];
    const float* k_b2 = (const float*)d_in[13];
    const float* v_w  = (const float*)d_in[14];
    const float* v_g  = (const float*)d_in[15];
    const float* v_b  = (const float*)d_in[16];
    const float* o_w  = (const float*)d_in[17];
    const float* o_g  = (const float*)d_in[18];
    const float* o_b  = (const float*)d_in[19];

    // ws layout (21.2 MB, r12-proven): y1/kmid are fp32 mids that alias the
    // bf16 partial buffers (dead before flash writes them).
    char* ws = (char*)d_ws;
    unsigned short* P0  = (unsigned short*)ws;                          // 0-3 MB
    unsigned short* P1  = (unsigned short*)(ws + 3145728);              // 3-6
    unsigned short* Qbf = (unsigned short*)(ws + 6291456);              // 6-9
    unsigned short* Kbf = (unsigned short*)(ws + 6291456 + 3145728);    // 9-12
    unsigned short* Vbf = (unsigned short*)(ws + 6291456 + 2 * 3145728);// 12-15
    unsigned short* P2  = (unsigned short*)(ws + 6291456 + 3 * 3145728);// 15-18
    unsigned short* P3  = (unsigned short*)(ws + 6291456 + 4 * 3145728);// 18-21
    float*          L0  = (float*)(ws + 6291456 + 5 * 3145728);         // 48 KB x4
    float*          L1  = L0 + HW_DIM * 2;
    float*          L2  = L1 + HW_DIM * 2;
    float*          L3  = L2 + HW_DIM * 2;
    float*          y1   = (float*)ws;                    // 0-6 MB  (q mid)
    float*          kmid = (float*)(ws + 6291456 + 3 * 3145728); // 15-21 (k mid)
    float* outp = (float*)d_out;

    const float qscale = 0.08838834764831845f * 1.44269504088896340f;

    // Launch A: q-conv1, k-conv1, v-conv (independent) in one dispatch.
    {
        ConvJobs J;
        J.X[0] = query; J.W[0] = q_w1; J.G[0] = q_g1; J.B[0] = q_b1;
        J.out[0] = (void*)y1;   J.oscale[0] = 1.0f; J.out_mode[0] = 0;
        J.X[1] = key;   J.W[1] = k_w1; J.G[1] = k_g1; J.B[1] = k_b1;
        J.out[1] = (void*)kmid; J.oscale[1] = 1.0f; J.out_mode[1] = 0;
        J.X[2] = key;   J.W[2] = v_w;  J.G[2] = v_g;  J.B[2] = v_b;
        J.out[2] = (void*)Vbf;  J.oscale[2] = 1.0f; J.out_mode[2] = 2;
        hipLaunchKernelGGL(conv_jobs, dim3(HW_DIM / 32, 2, 3), dim3(256),
                           0, stream, J);
    }
    // Launch B: q-conv2, k-conv2.
    {
        ConvJobs J;
        J.X[0] = y1;   J.W[0] = q_w2; J.G[0] = q_g2; J.B[0] = q_b2;
        J.out[0] = (void*)Qbf; J.oscale[0] = qscale; J.out_mode[0] = 1;
        J.X[1] = kmid; J.W[1] = k_w2; J.G[1] = k_g2; J.B[1] = k_b2;
        J.out[1] = (void*)Kbf; J.oscale[1] = 1.0f;   J.out_mode[1] = 1;
        J.X[2] = y1;   J.W[2] = q_w2; J.G[2] = q_g2; J.B[2] = q_b2;
        J.out[2] = (void*)Qbf; J.oscale[2] = qscale; J.out_mode[2] = 1;
        hipLaunchKernelGGL(conv_jobs, dim3(HW_DIM / 32, 2, 2), dim3(256),
                           0, stream, J);
    }

    // Flash: 192 q-rows x k-quarter per block, 8 waves (2 k-eighth groups).
    hipLaunchKernelGGL(flash_attn, dim3(256), dim3(512), 0, stream,
                       Qbf, Kbf, Vbf, P0, P1, P2, P3, L0, L1, L2, L3);

    // Out-projection: combine 4 bf16 partials + residual.
    hipLaunchKernelGGL(conv_combine, dim3(HW_DIM / 32, 2), dim3(256), 0, stream,
                       P0, P1, P2, P3, L0, L1, L2, L3,
                       o_w, o_g, o_b, outp, query);
}

// Round 15
// 223.766 us; speedup vs baseline: 1.2077x; 1.1059x over previous
//
#include <hip/hip_runtime.h>

#define C_DIM 128
#define HW_DIM 6144

typedef __attribute__((ext_vector_type(8))) short short8;
typedef __attribute__((ext_vector_type(4))) float f32x4;

static __device__ __forceinline__ unsigned short f2bf(float x) {
    unsigned int u = __builtin_bit_cast(unsigned int, x);
    u = (u + 0x7FFFu + ((u >> 16) & 1u)) >> 16;
    return (unsigned short)u;
}
static __device__ __forceinline__ float bf2f(unsigned short u) {
    unsigned int x = ((unsigned int)u) << 16;
    return __builtin_bit_cast(float, x);
}
static __device__ __forceinline__ unsigned int pack2(float a, float b) {
    return (unsigned int)f2bf(a) | ((unsigned int)f2bf(b) << 16);
}
static __device__ __forceinline__ f32x4 mfma_bf16(short8 a, short8 b, f32x4 c) {
    return __builtin_amdgcn_mfma_f32_16x16x32_bf16(a, b, c, 0, 0, 0);
}

// ---------------------------------------------------------------------------
// MFMA 1x1-conv + BN + LeakyReLU. M=128 out-ch, N=64 positions/block, K=128.
// W and X staged to LDS as bf16 with the flash-verified XOR chunk swizzle.
// in_mode : 0 = X fp32 [b][c][hw] (transpose-stage)
//           1 = X bf16 [b][pos][c] (direct stage)
//           2 = combine: (P0+P1+P2+P3)[pos][c] bf16 * invL[pos]
// out_mode: 0 = bf16 [b][pos][c] * oscale (via LDS transpose, coalesced)
//           1 = bf16 [b][c][pos]          (via LDS transpose, coalesced)
//           2 = fp32 [b][c][hw] + residual (direct from C frags)
// r14 BUG FIX: out_mode 1 store loop ran i<2 (covered only o=0..63; V
// channels 64-127 stayed poison -> absmax 0.78). Now i<4: all 1024 chunks.
// ---------------------------------------------------------------------------
struct MJob {
    const void* X; const void* X1; const void* X2; const void* X3;
    const float* L0; const float* L1; const float* L2; const float* L3;
    const float* W; const float* G; const float* B;
    void* out; const float* resid;
    float oscale; int in_mode; int out_mode;
};
struct MJobs { MJob j[3]; };

__global__ __launch_bounds__(256)
void conv_mfma(MJobs jobs)
{
    const MJob jb = (blockIdx.z == 0) ? jobs.j[0]
                  : (blockIdx.z == 1) ? jobs.j[1] : jobs.j[2];

    __shared__ __align__(16) unsigned short Wt[128 * 128];  // 32 KB [o][c]
    __shared__ __align__(16) unsigned short Xt[64 * 128];   // 16 KB [p][c]
    __shared__ __align__(16) unsigned short Ct[128 * 64];   // 16 KB epilogue
    __shared__ float invl[64];

    const int t    = threadIdx.x;
    const int b    = blockIdx.y;
    const int p0   = blockIdx.x * 64;
    const int wave = t >> 6;
    const int lane = t & 63;
    const int quad = lane >> 4;
    const int l16  = lane & 15;

    // ---- stage W: fp32 [o][c] -> bf16 Wt[o][chunk^(o&15)] ----
    const float* Wg = jb.W;
#pragma unroll
    for (int i = 0; i < 16; ++i) {
        int f = i * 1024 + t * 4;             // o = f>>7, c = f&127 (mult of 4)
        int o = f >> 7, c = f & 127;
        float4 w4 = *(const float4*)&Wg[o * C_DIM + c];
        int addr = o * 128 + (((c >> 3) ^ (o & 15)) * 8) + (c & 7);
        *(unsigned int*)&Wt[addr]     = pack2(w4.x, w4.y);
        *(unsigned int*)&Wt[addr + 2] = pack2(w4.z, w4.w);
    }

    // ---- stage X per in_mode -> bf16 Xt[p][chunk^(p&15)] ----
    if (jb.in_mode == 0) {
        const float* Xg = (const float*)jb.X + (size_t)b * C_DIM * HW_DIM;
#pragma unroll
        for (int i = 0; i < 8; ++i) {
            int f = i * 1024 + t * 4;         // c = f>>6, p = f&63 (mult of 4)
            int c = f >> 6, p = f & 63;
            float4 x4 = *(const float4*)&Xg[(size_t)c * HW_DIM + p0 + p];
            float xv[4] = {x4.x, x4.y, x4.z, x4.w};
#pragma unroll
            for (int j = 0; j < 4; ++j) {
                int pp = p + j;
                Xt[pp * 128 + (((c >> 3) ^ (pp & 15)) * 8) + (c & 7)] = f2bf(xv[j]);
            }
        }
    } else if (jb.in_mode == 1) {
        const unsigned short* Xg = (const unsigned short*)jb.X;
#pragma unroll
        for (int i = 0; i < 4; ++i) {
            int idx = t + 256 * i;            // p = idx>>4, ch = idx&15
            int p = idx >> 4, ch = idx & 15;
            uint4 v = *(const uint4*)&Xg[((size_t)b * HW_DIM + p0 + p) * C_DIM + ch * 8];
            *(uint4*)&Xt[p * 128 + ((ch ^ (p & 15)) * 8)] = v;
        }
    } else {
        if (t < 64) {
            size_t li = (size_t)b * HW_DIM + p0 + t;
            invl[t] = 1.0f / (jb.L0[li] + jb.L1[li] + jb.L2[li] + jb.L3[li]);
        }
        __syncthreads();
        const unsigned short* A0 = (const unsigned short*)jb.X;
        const unsigned short* A1 = (const unsigned short*)jb.X1;
        const unsigned short* A2 = (const unsigned short*)jb.X2;
        const unsigned short* A3 = (const unsigned short*)jb.X3;
#pragma unroll
        for (int i = 0; i < 4; ++i) {
            int idx = t + 256 * i;
            int p = idx >> 4, ch = idx & 15;
            size_t gi = ((size_t)b * HW_DIM + p0 + p) * C_DIM + ch * 8;
            uint4 a = *(const uint4*)&A0[gi];
            uint4 c2 = *(const uint4*)&A1[gi];
            uint4 d = *(const uint4*)&A2[gi];
            uint4 e = *(const uint4*)&A3[gi];
            float s = invl[p];
            unsigned int w[4];
            const unsigned int* ap = (const unsigned int*)&a;
            const unsigned int* bp = (const unsigned int*)&c2;
            const unsigned int* cp = (const unsigned int*)&d;
            const unsigned int* dp = (const unsigned int*)&e;
#pragma unroll
            for (int j = 0; j < 4; ++j) {
                float lo = bf2f((unsigned short)(ap[j] & 0xFFFF))
                         + bf2f((unsigned short)(bp[j] & 0xFFFF))
                         + bf2f((unsigned short)(cp[j] & 0xFFFF))
                         + bf2f((unsigned short)(dp[j] & 0xFFFF));
                float hi = bf2f((unsigned short)(ap[j] >> 16))
                         + bf2f((unsigned short)(bp[j] >> 16))
                         + bf2f((unsigned short)(cp[j] >> 16))
                         + bf2f((unsigned short)(dp[j] >> 16));
                w[j] = pack2(lo * s, hi * s);
            }
            *(uint4*)&Xt[p * 128 + ((ch ^ (p & 15)) * 8)] = *(uint4*)w;
        }
    }
    __syncthreads();

    // ---- MFMA: wave handles m-tiles {2w, 2w+1} x 4 n-tiles, K=128 ----
    short8 af[2][4];
#pragma unroll
    for (int mi = 0; mi < 2; ++mi)
#pragma unroll
        for (int s = 0; s < 4; ++s)
            af[mi][s] = *(const short8*)
                &Wt[((wave * 2 + mi) * 16 + l16) * 128 + (((4 * s + quad) ^ l16) * 8)];

    f32x4 acc[2][4];
#pragma unroll
    for (int mi = 0; mi < 2; ++mi)
#pragma unroll
        for (int nt = 0; nt < 4; ++nt) acc[mi][nt] = (f32x4){0.f, 0.f, 0.f, 0.f};
#pragma unroll
    for (int nt = 0; nt < 4; ++nt)
#pragma unroll
        for (int s = 0; s < 4; ++s) {
            short8 bf = *(const short8*)
                &Xt[(nt * 16 + l16) * 128 + (((4 * s + quad) ^ l16) * 8)];
            acc[0][nt] = mfma_bf16(af[0][s], bf, acc[0][nt]);
            acc[1][nt] = mfma_bf16(af[1][s], bf, acc[1][nt]);
        }

    // ---- BN + LeakyReLU on C fragments (row o = mt*16+quad*4+r, col l16) ----
    const float BNRS = 0.99999500003749972f;  // 1/sqrt(1 + 1e-5)
#pragma unroll
    for (int mi = 0; mi < 2; ++mi)
#pragma unroll
        for (int r = 0; r < 4; ++r) {
            int o = (wave * 2 + mi) * 16 + quad * 4 + r;
            float sc = jb.G[o] * BNRS, bb = jb.B[o];
#pragma unroll
            for (int nt = 0; nt < 4; ++nt) {
                float y = fmaf(acc[mi][nt][r], sc, bb);
                acc[mi][nt][r] = y > 0.f ? y : 0.1f * y;
            }
        }

    // ---- epilogue ----
    if (jb.out_mode == 0) {
        // bf16 [b][pos][c] * oscale, via Ct[p][o-chunk^(p&15)]
        unsigned short* O = (unsigned short*)jb.out;
        float os = jb.oscale;
#pragma unroll
        for (int mi = 0; mi < 2; ++mi)
#pragma unroll
            for (int nt = 0; nt < 4; ++nt)
#pragma unroll
                for (int r = 0; r < 4; ++r) {
                    int o = (wave * 2 + mi) * 16 + quad * 4 + r;
                    int p = nt * 16 + l16;
                    Ct[p * 128 + (((o >> 3) ^ (p & 15)) * 8) + (o & 7)] =
                        f2bf(acc[mi][nt][r] * os);
                }
        __syncthreads();
#pragma unroll
        for (int i = 0; i < 4; ++i) {
            int idx = t + 256 * i;
            int p = idx >> 4, ch = idx & 15;
            uint4 v = *(const uint4*)&Ct[p * 128 + ((ch ^ (p & 15)) * 8)];
            *(uint4*)&O[((size_t)b * HW_DIM + p0 + p) * C_DIM + ch * 8] = v;
        }
    } else if (jb.out_mode == 1) {
        // bf16 [b][c][pos], via Ct[o][p-chunk^(o&7)]
        unsigned short* O = (unsigned short*)jb.out;
#pragma unroll
        for (int mi = 0; mi < 2; ++mi)
#pragma unroll
            for (int nt = 0; nt < 4; ++nt)
#pragma unroll
                for (int r = 0; r < 4; ++r) {
                    int o = (wave * 2 + mi) * 16 + quad * 4 + r;
                    int p = nt * 16 + l16;
                    Ct[o * 64 + (((p >> 3) ^ (o & 7)) * 8) + (p & 7)] =
                        f2bf(acc[mi][nt][r]);
                }
        __syncthreads();
#pragma unroll
        for (int i = 0; i < 4; ++i) {          // FIX: was i<2 (o only 0..63)
            int idx = t + 256 * i;
            int o = idx >> 3, ch = idx & 7;
            uint4 v = *(const uint4*)&Ct[o * 64 + ((ch ^ (o & 7)) * 8)];
            *(uint4*)&O[((size_t)b * C_DIM + o) * HW_DIM + p0 + ch * 8] = v;
        }
    } else {
        // fp32 [b][c][hw] + residual, direct
        float* O = (float*)jb.out;
#pragma unroll
        for (int mi = 0; mi < 2; ++mi)
#pragma unroll
            for (int nt = 0; nt < 4; ++nt)
#pragma unroll
                for (int r = 0; r < 4; ++r) {
                    int o = (wave * 2 + mi) * 16 + quad * 4 + r;
                    size_t g = ((size_t)b * C_DIM + o) * HW_DIM + p0 + nt * 16 + l16;
                    O[g] = acc[mi][nt][r] + jb.resid[g];
                }
    }
}

// ---------------------------------------------------------------------------
// Flash attention v5 (r13, byte-identical): 512 thr = 2 wave-groups of 4,
// groups split the block's k-quarter into eighths with own swizzled tiles,
// rt=3 row-tiles/wave, 4-way global split-K, internal group combine.
// ---------------------------------------------------------------------------
__global__ __launch_bounds__(512, 2)
void flash_attn(const unsigned short* __restrict__ Q,
                const unsigned short* __restrict__ K,
                const unsigned short* __restrict__ V,
                unsigned short* __restrict__ P0, unsigned short* __restrict__ P1,
                unsigned short* __restrict__ P2, unsigned short* __restrict__ P3,
                float* __restrict__ L0, float* __restrict__ L1,
                float* __restrict__ L2, float* __restrict__ L3)
{
    __shared__ __align__(16) unsigned short TM[2][16384];     // 64 KB
    __shared__ __align__(16) unsigned short Plds[8][16][72];  // 18 KB
    const int tid  = threadIdx.x;
    const int wave = tid >> 6;
    const int gid  = wave >> 2;
    const int wl   = wave & 3;
    const int gtid = tid & 255;
    const int lane = tid & 63;
    const int quad = lane >> 4;
    const int l16  = lane & 15;

    const int bid  = blockIdx.x;
    const int xcd  = bid & 7;
    const int b    = xcd >> 2;
    const int g3   = xcd & 3;
    const int i    = bid >> 3;
    const int ks   = i >> 3;
    const int qblk = g3 * 8 + (i & 7);
    const int q0   = qblk * 192 + wl * 48;
    const int kbeg = ks * (HW_DIM / 4) + gid * (HW_DIM / 8);

    unsigned short* __restrict__ Po = (ks == 0) ? P0 : (ks == 1) ? P1
                                    : (ks == 2) ? P2 : P3;
    float* __restrict__ Lo = (ks == 0) ? L0 : (ks == 1) ? L1
                           : (ks == 2) ? L2 : L3;

    const unsigned short* Qb = Q + (size_t)b * HW_DIM * C_DIM;
    const unsigned short* Kb = K + (size_t)b * HW_DIM * C_DIM;
    const unsigned short* Vb = V + (size_t)b * C_DIM * HW_DIM;

    unsigned short* Kt = TM[gid];
    unsigned short* Vt = TM[gid] + 8192;

    short8 qf[3][4];
#pragma unroll
    for (int rt = 0; rt < 3; ++rt)
#pragma unroll
        for (int s = 0; s < 4; ++s)
            qf[rt][s] = *(const short8*)
                &Qb[(size_t)(q0 + rt * 16 + l16) * C_DIM + s * 32 + quad * 8];

    f32x4 O[3][8];
#pragma unroll
    for (int rt = 0; rt < 3; ++rt)
#pragma unroll
        for (int h = 0; h < 8; ++h) O[rt][h] = (f32x4){0.f, 0.f, 0.f, 0.f};
    float lsum[3][4] = {{0,0,0,0},{0,0,0,0},{0,0,0,0}};

    uint4 kst[4], vst[4];
#pragma unroll
    for (int j = 0; j < 4; ++j) {
        int ck = gtid + 256 * j;
        kst[j] = *(const uint4*)&Kb[(size_t)(kbeg + (ck >> 4)) * C_DIM + (ck & 15) * 8];
        vst[j] = *(const uint4*)&Vb[(size_t)(ck >> 3) * HW_DIM + kbeg + (ck & 7) * 8];
    }

    const int NIT = (HW_DIM / 8) / 64;   // 12
    for (int it = 0; it < NIT; ++it) {
#pragma unroll
        for (int j = 0; j < 4; ++j) {
            int ck = gtid + 256 * j;
            *(uint4*)&Kt[(size_t)(ck >> 4) * 128 + (((ck & 15) ^ ((ck >> 4) & 15)) * 8)] = kst[j];
            *(uint4*)&Vt[(size_t)(ck >> 3) * 64 + (((ck & 7) ^ ((ck >> 3) & 7)) * 8)]   = vst[j];
        }
        __syncthreads();

        if (it + 1 < NIT) {
            const int kb2 = kbeg + (it + 1) * 64;
#pragma unroll
            for (int j = 0; j < 4; ++j) {
                int ck = gtid + 256 * j;
                kst[j] = *(const uint4*)
                    &Kb[(size_t)(kb2 + (ck >> 4)) * C_DIM + (ck & 15) * 8];
                vst[j] = *(const uint4*)
                    &Vb[(size_t)(ck >> 3) * HW_DIM + kb2 + (ck & 7) * 8];
            }
        }

        f32x4 S[3][4];
#pragma unroll
        for (int rt = 0; rt < 3; ++rt)
#pragma unroll
            for (int n = 0; n < 4; ++n) S[rt][n] = (f32x4){0.f, 0.f, 0.f, 0.f};
#pragma unroll
        for (int n = 0; n < 4; ++n)
#pragma unroll
            for (int s = 0; s < 4; ++s) {
                short8 kf = *(const short8*)
                    &Kt[(size_t)(n * 16 + l16) * 128 + (((4 * s + quad) ^ l16) * 8)];
                S[0][n] = mfma_bf16(qf[0][s], kf, S[0][n]);
                S[1][n] = mfma_bf16(qf[1][s], kf, S[1][n]);
                S[2][n] = mfma_bf16(qf[2][s], kf, S[2][n]);
            }

        short8 pa[3][2];
#pragma unroll
        for (int rt = 0; rt < 3; ++rt) {
#pragma unroll
            for (int n = 0; n < 4; ++n)
#pragma unroll
                for (int r = 0; r < 4; ++r) {
                    float e = __builtin_amdgcn_exp2f(S[rt][n][r]);
                    lsum[rt][r] += e;
                    Plds[wave][quad * 4 + r][n * 16 + l16] = f2bf(e);
                }
            pa[rt][0] = *(const short8*)&Plds[wave][l16][quad * 8];
            pa[rt][1] = *(const short8*)&Plds[wave][l16][32 + quad * 8];
        }

        const int m = l16 & 7;
#pragma unroll
        for (int h = 0; h < 8; ++h) {
            short8 v0 = *(const short8*)&Vt[(size_t)(h * 16 + l16) * 64 + ((quad ^ m) * 8)];
            short8 v1 = *(const short8*)&Vt[(size_t)(h * 16 + l16) * 64 + (((quad + 4) ^ m) * 8)];
            O[0][h] = mfma_bf16(pa[0][0], v0, O[0][h]);
            O[0][h] = mfma_bf16(pa[0][1], v1, O[0][h]);
            O[1][h] = mfma_bf16(pa[1][0], v0, O[1][h]);
            O[1][h] = mfma_bf16(pa[1][1], v1, O[1][h]);
            O[2][h] = mfma_bf16(pa[2][0], v0, O[2][h]);
            O[2][h] = mfma_bf16(pa[2][1], v1, O[2][h]);
        }
        __syncthreads();
    }

#pragma unroll
    for (int off = 1; off < 16; off <<= 1)
#pragma unroll
        for (int rt = 0; rt < 3; ++rt)
#pragma unroll
            for (int r = 0; r < 4; ++r)
                lsum[rt][r] += __shfl_xor(lsum[rt][r], off, 64);

    unsigned short* CB = &TM[0][0];
    float* Lsh = (float*)&Plds[0][0][0];
    __syncthreads();
    if (gid == 1) {
#pragma unroll
        for (int rt = 0; rt < 3; ++rt)
#pragma unroll
            for (int r = 0; r < 4; ++r) {
                int lrow = wl * 48 + rt * 16 + quad * 4 + r;
                if (l16 == 0) Lsh[lrow] = lsum[rt][r];
#pragma unroll
                for (int h = 0; h < 8; ++h)
                    CB[lrow * 132 + h * 16 + l16] = f2bf(O[rt][h][r]);
            }
    }
    __syncthreads();
    if (gid == 0) {
#pragma unroll
        for (int rt = 0; rt < 3; ++rt)
#pragma unroll
            for (int r = 0; r < 4; ++r) {
                int lrow = wl * 48 + rt * 16 + quad * 4 + r;
                size_t row = (size_t)b * HW_DIM + qblk * 192 + lrow;
                if (l16 == 0) Lo[row] = lsum[rt][r] + Lsh[lrow];
#pragma unroll
                for (int h = 0; h < 8; ++h) {
                    float s = O[rt][h][r] + bf2f(CB[lrow * 132 + h * 16 + l16]);
                    Po[row * C_DIM + h * 16 + l16] = f2bf(s);
                }
            }
    }
}

// ---------------------------------------------------------------------------
extern "C" void kernel_launch(void* const* d_in, const int* in_sizes, int n_in,
                              void* d_out, int out_size, void* d_ws, size_t ws_size,
                              hipStream_t stream)
{
    const float* query = (const float*)d_in[0];
    const float* key   = (const float*)d_in[1];
    const float* q_w1 = (const float*)d_in[2];
    const float* q_g1 = (const float*)d_in[3];
    const float* q_b1 = (const float*)d_in[4];
    const float* q_w2 = (const float*)d_in[5];
    const float* q_g2 = (const float*)d_in[6];
    const float* q_b2 = (const float*)d_in[7];
    const float* k_w1 = (const float*)d_in[8];
    const float* k_g1 = (const float*)d_in[9];
    const float* k_b1 = (const float*)d_in[10];
    const float* k_w2 = (const float*)d_in[11];
    const float* k_g2 = (const float*)d_in[12];
    const float* k_b2 = (const float*)d_in[13];
    const float* v_w  = (const float*)d_in[14];
    const float* v_g  = (const float*)d_in[15];
    const float* v_b  = (const float*)d_in[16];
    const float* o_w  = (const float*)d_in[17];
    const float* o_g  = (const float*)d_in[18];
    const float* o_b  = (const float*)d_in[19];

    // ws (21.2 MB): Qmid/Kmid (bf16 [pos][c] mids) alias P0/P1 (dead before
    // flash writes them).
    char* ws = (char*)d_ws;
    unsigned short* P0  = (unsigned short*)ws;                          // 0-3 MB
    unsigned short* P1  = (unsigned short*)(ws + 3145728);              // 3-6
    unsigned short* Qbf = (unsigned short*)(ws + 6291456);              // 6-9
    unsigned short* Kbf = (unsigned short*)(ws + 6291456 + 3145728);    // 9-12
    unsigned short* Vbf = (unsigned short*)(ws + 6291456 + 2 * 3145728);// 12-15
    unsigned short* P2  = (unsigned short*)(ws + 6291456 + 3 * 3145728);// 15-18
    unsigned short* P3  = (unsigned short*)(ws + 6291456 + 4 * 3145728);// 18-21
    float*          L0  = (float*)(ws + 6291456 + 5 * 3145728);
    float*          L1  = L0 + HW_DIM * 2;
    float*          L2  = L1 + HW_DIM * 2;
    float*          L3  = L2 + HW_DIM * 2;
    unsigned short* Qmid = P0;
    unsigned short* Kmid = P1;
    float* outp = (float*)d_out;

    const float qscale = 0.08838834764831845f * 1.44269504088896340f;

    // Launch A: q-conv1 -> Qmid, k-conv1 -> Kmid, v-conv -> Vbf.
    {
        MJobs J{};
        J.j[0] = {query, nullptr, nullptr, nullptr, nullptr, nullptr, nullptr, nullptr,
                  q_w1, q_g1, q_b1, (void*)Qmid, nullptr, 1.0f, 0, 0};
        J.j[1] = {key, nullptr, nullptr, nullptr, nullptr, nullptr, nullptr, nullptr,
                  k_w1, k_g1, k_b1, (void*)Kmid, nullptr, 1.0f, 0, 0};
        J.j[2] = {key, nullptr, nullptr, nullptr, nullptr, nullptr, nullptr, nullptr,
                  v_w, v_g, v_b, (void*)Vbf, nullptr, 1.0f, 0, 1};
        hipLaunchKernelGGL(conv_mfma, dim3(HW_DIM / 64, 2, 3), dim3(256),
                           0, stream, J);
    }
    // Launch B: q-conv2 -> Qbf (scaled), k-conv2 -> Kbf.
    {
        MJobs J{};
        J.j[0] = {Qmid, nullptr, nullptr, nullptr, nullptr, nullptr, nullptr, nullptr,
                  q_w2, q_g2, q_b2, (void*)Qbf, nullptr, qscale, 1, 0};
        J.j[1] = {Kmid, nullptr, nullptr, nullptr, nullptr, nullptr, nullptr, nullptr,
                  k_w2, k_g2, k_b2, (void*)Kbf, nullptr, 1.0f, 1, 0};
        J.j[2] = J.j[1];
        hipLaunchKernelGGL(conv_mfma, dim3(HW_DIM / 64, 2, 2), dim3(256),
                           0, stream, J);
    }

    // Flash (r13 structure, unchanged).
    hipLaunchKernelGGL(flash_attn, dim3(256), dim3(512), 0, stream,
                       Qbf, Kbf, Vbf, P0, P1, P2, P3, L0, L1, L2, L3);

    // Launch C: combine partials -> out-conv + residual.
    {
        MJobs J{};
        J.j[0] = {P0, P1, P2, P3, L0, L1, L2, L3,
                  o_w, o_g, o_b, (void*)outp, query, 1.0f, 2, 2};
        J.j[1] = J.j[0];
        J.j[2] = J.j[0];
        hipLaunchKernelGGL(conv_mfma, dim3(HW_DIM / 64, 2, 1), dim3(256),
                           0, stream, J);
    }
}